// Round 10
// baseline (576.582 us; speedup 1.0000x reference)
//
#include <hip/hip_runtime.h>

// ---------------------------------------------------------------------------
// ContrastiveLoss (SCAN t2i cross-attention) on MI355X — round 10.
// N=256x256 pairs, R=36 regions, L=50 words, D=256.
// r10 vs r9: xattn_main processes TWO pairs (same image, j and j+1) per wave,
// interleaving pair-Q's phase-A (global loads + MFMA) inside pair-P's softmax
// m-loop — hides the memory phase under the VALU phase (the measured stall).
// gA loaded once per wave (reused for both matvecs). One LDS region per wave
// (48 rows, reused P->Q). Long captions (len>48, ~4%) still via xattn4.
// ---------------------------------------------------------------------------

typedef unsigned short u16;
typedef unsigned int u32;

typedef __attribute__((ext_vector_type(8))) __bf16 bf16x8;
typedef __attribute__((ext_vector_type(4))) __bf16 bf16x4;
typedef __attribute__((ext_vector_type(4))) float floatx4;

#define NN 256
#define RR 36
#define LL 50
#define DD 256
#define RP 48    // padded region dim
#define LP 64    // padded word dim (s rows)
#define KP 64    // gram row stride / matvec K
#define ASTR 68  // u16 stride of LDS rows
#define WROWS 50 // xattn4 LDS rows per wave
#define SLOP 14  // xattn4 shared overflow rows
#define PSTR 264 // u16 stride for prep LDS stage

__device__ __forceinline__ u16 f2bf(float v) {
  u32 u = __builtin_bit_cast(u32, v);
  u += 0x7fffu + ((u >> 16) & 1u);   // RNE (inputs never NaN)
  return (u16)(u >> 16);
}
__device__ __forceinline__ float bflo(u32 w) { return __builtin_bit_cast(float, w << 16); }
__device__ __forceinline__ float bfhi(u32 w) { return __builtin_bit_cast(float, w & 0xffff0000u); }

#define WAVE_SYNC() do { \
  asm volatile("s_waitcnt lgkmcnt(0)" ::: "memory"); \
  __builtin_amdgcn_sched_barrier(0); \
} while (0)

// ---- fused prep: blocks 0..255 im+gram; blocks 256..511 s+cn+longlist -----
__global__ void prep_kernel(const float* __restrict__ im,
                            const float* __restrict__ s,
                            const int* __restrict__ cap,
                            u16* __restrict__ im_bf,
                            u16* __restrict__ gram_bf,
                            u16* __restrict__ s_bf,
                            float* __restrict__ cn,
                            int* __restrict__ longcnt,
                            int* __restrict__ longlist) {
  __shared__ u16 Lb[RP * PSTR];
  const int t = threadIdx.x;
  if (blockIdx.x < NN) {
    const int i = blockIdx.x;
    const float* src = im + (size_t)i * (RR * DD);
    u16* dst = im_bf + (size_t)i * (RP * DD);
    for (int e = t; e < RR * DD; e += 256) {
      int r = e >> 8, d = e & 255;
      u16 b = f2bf(src[e]);
      dst[e] = b;
      Lb[r * PSTR + d] = b;
    }
    for (int e = RR * DD + t; e < RP * DD; e += 256) {
      int r = e >> 8, d = e & 255;
      dst[e] = 0;
      Lb[r * PSTR + d] = 0;
    }
    __syncthreads();
    if (t >= 64) return;   // wave 0 computes Gram via MFMA from LDS
    const int lane = t;
    const int lo = lane & 15, hi = lane >> 4;
    floatx4 acc[3][3];
    #pragma unroll
    for (int m = 0; m < 3; ++m)
      #pragma unroll
      for (int n = 0; n < 3; ++n) acc[m][n] = floatx4{0.f, 0.f, 0.f, 0.f};
    #pragma unroll 2
    for (int kt = 0; kt < 8; ++kt) {
      const int k0 = (kt << 5) + (hi << 3);
      bf16x8 f[3];
      #pragma unroll
      for (int m = 0; m < 3; ++m)
        f[m] = __builtin_bit_cast(bf16x8, *(const uint4*)&Lb[(m * 16 + lo) * PSTR + k0]);
      #pragma unroll
      for (int m = 0; m < 3; ++m)
        #pragma unroll
        for (int n = 0; n < 3; ++n)
          acc[m][n] = __builtin_amdgcn_mfma_f32_16x16x32_bf16(f[m], f[n], acc[m][n], 0, 0, 0);
    }
    u16* g = gram_bf + (size_t)i * (RP * KP);
    #pragma unroll
    for (int m = 0; m < 3; ++m)
      #pragma unroll
      for (int n = 0; n < 3; ++n)
        #pragma unroll
        for (int q = 0; q < 4; ++q)
          g[(m * 16 + hi * 4 + q) * KP + n * 16 + lo] = f2bf(acc[m][n][q]);
    for (int e = lane; e < RP * 16; e += 64) {
      int r = e >> 4, c = e & 15;
      g[r * KP + 48 + c] = 0;
    }
  } else {
    const int j = blockIdx.x - NN;
    const float* src = s + (size_t)j * (LL * DD);
    u16* dst = s_bf + (size_t)j * (LP * DD);
    for (int e = t; e < LL * DD; e += 256) dst[e] = f2bf(src[e]);
    for (int e = LL * DD + t; e < LP * DD; e += 256) dst[e] = 0;
    const int l = t >> 2, q = t & 3;
    float acc = 0.f;
    if (l < LL) {
      const float* row = src + l * DD + q * 64;
      #pragma unroll 4
      for (int d = 0; d < 64; ++d) { float v = row[d]; acc = fmaf(v, v, acc); }
    }
    acc += __shfl_xor(acc, 1);
    acc += __shfl_xor(acc, 2);
    if (l < LL && q == 0) cn[j * LL + l] = sqrtf(acc);
    if (t == 0 && cap[j] > 48) {
      int k = atomicAdd(longcnt, 1);
      longlist[k] = j;
    }
  }
}

// ---- xattn_main: 2 pairs per wave (same i, j0=even, j1=j0+1), nv=3 --------
__global__ __launch_bounds__(256, 4) void xattn_main_kernel(
    const u16* __restrict__ im_bf, const u16* __restrict__ s_bf,
    const u16* __restrict__ gram_bf, const float* __restrict__ cn,
    const int* __restrict__ cap, float* __restrict__ scores) {
  __shared__ u16 buf[4 * 48 * ASTR];  // 26,112 B (one 48-row region per wave)

  const int wid  = threadIdx.x >> 6;
  const int lane = threadIdx.x & 63;
  const int lo = lane & 15, hi = lane >> 4;
  const int i  = blockIdx.x >> 5;
  const int j0 = ((blockIdx.x & 31) << 3) | (wid << 1);
  const int j1 = j0 | 1;
  const int lenP = cap[j0];
  const int lenQ = cap[j1];
  const bool hiz = (hi == 0);

  u16* mybuf = buf + wid * (48 * ASTR);

  // zero K-pad cols 48..63 of all 48 rows (done once; Q reuses the region)
  if (lane < 48) {
    uint2 z2 = {0u, 0u};
    uint2* zp = (uint2*)&mybuf[lane * ASTR + 48];
    zp[0] = z2; zp[1] = z2; zp[2] = z2; zp[3] = z2;
  }

  const u16* imp = im_bf + (size_t)i * (RP * DD);
  const u16* spP = s_bf + (size_t)j0 * (LP * DD);
  const u16* spQ = s_bf + (size_t)j1 * (LP * DD);

  // ======== Phase A (pair P): G_P = im_i @ s_j0^T ==========================
  floatx4 aP[3][3];
  #pragma unroll
  for (int m = 0; m < 3; ++m)
    #pragma unroll
    for (int n = 0; n < 3; ++n) aP[m][n] = floatx4{0.f, 0.f, 0.f, 0.f};

  #pragma unroll 2
  for (int kt = 0; kt < 8; ++kt) {
    const int k0 = (kt << 5) + (hi << 3);
    bf16x8 af[3], bfr[3];
    #pragma unroll
    for (int m = 0; m < 3; ++m)
      af[m] = __builtin_bit_cast(bf16x8, *(const uint4*)(imp + (m * 16 + lo) * DD + k0));
    #pragma unroll
    for (int n = 0; n < 3; ++n)
      bfr[n] = __builtin_bit_cast(bf16x8, *(const uint4*)(spP + (n * 16 + lo) * DD + k0));
    #pragma unroll
    for (int m = 0; m < 3; ++m)
      #pragma unroll
      for (int n = 0; n < 3; ++n)
        aP[m][n] = __builtin_amdgcn_mfma_f32_16x16x32_bf16(af[m], bfr[n], aP[m][n], 0, 0, 0);
  }

  // ======== ss_P -> rinv_P =================================================
  float ssP[3][4];
  #pragma unroll
  for (int m = 0; m < 3; ++m)
    #pragma unroll
    for (int q = 0; q < 4; ++q) ssP[m][q] = 0.f;
  {
    float mk[3];
    #pragma unroll
    for (int n = 0; n < 3; ++n) mk[n] = (n * 16 + lo < lenP) ? 1.f : 0.f;
    #pragma unroll
    for (int m = 0; m < 3; ++m)
      #pragma unroll
      for (int n = 0; n < 3; ++n)
        #pragma unroll
        for (int q = 0; q < 4; ++q) {
          float g = aP[m][n][q];
          float v = fmaxf(g, 0.1f * g);
          ssP[m][q] = fmaf(v * v, mk[n], ssP[m][q]);
        }
  }
  #pragma unroll
  for (int off = 1; off < 16; off <<= 1)
    #pragma unroll
    for (int m = 0; m < 3; ++m)
      #pragma unroll
      for (int q = 0; q < 4; ++q)
        ssP[m][q] += __shfl_xor(ssP[m][q], off);
  float rinvP[3][4];
  #pragma unroll
  for (int m = 0; m < 3; ++m)
    #pragma unroll
    for (int q = 0; q < 4; ++q)
      rinvP[m][q] = 12.984255368000671f / (sqrtf(ssP[m][q]) + 1e-8f); // 9*log2e/(||.||+eps)

  // ======== INTERLEAVE: softmax_P (m-slices) + Phase A (pair Q) ===========
  floatx4 aQ[3][3];
  #pragma unroll
  for (int m = 0; m < 3; ++m)
    #pragma unroll
    for (int n = 0; n < 3; ++n) aQ[m][n] = floatx4{0.f, 0.f, 0.f, 0.f};

  float numP[3], psP[3];
  #pragma unroll
  for (int n = 0; n < 3; ++n) { numP[n] = 0.f; psP[n] = 0.f; }

  #pragma unroll
  for (int m = 0; m < 3; ++m) {
    // ---- pair-Q phase-A chunk (kt = 3m .. ; m==2 takes 6,7) ----
    const int kb = m * 3;
    const int ke = (m == 2) ? 8 : m * 3 + 3;
    for (int kt = kb; kt < ke; ++kt) {
      const int k0 = (kt << 5) + (hi << 3);
      bf16x8 af[3], bq[3];
      #pragma unroll
      for (int mm = 0; mm < 3; ++mm)
        af[mm] = __builtin_bit_cast(bf16x8, *(const uint4*)(imp + (mm * 16 + lo) * DD + k0));
      #pragma unroll
      for (int n = 0; n < 3; ++n)
        bq[n] = __builtin_bit_cast(bf16x8, *(const uint4*)(spQ + (n * 16 + lo) * DD + k0));
      #pragma unroll
      for (int mm = 0; mm < 3; ++mm)
        #pragma unroll
        for (int n = 0; n < 3; ++n)
          aQ[mm][n] = __builtin_amdgcn_mfma_f32_16x16x32_bf16(af[mm], bq[n], aQ[mm][n], 0, 0, 0);
    }
    // ---- softmax_P slice m (frees aP[m]) ----
    #pragma unroll
    for (int n = 0; n < 3; ++n) {
      bf16x4 pb;
      #pragma unroll
      for (int q = 0; q < 4; ++q) {
        float g = aP[m][n][q];
        float v = fmaxf(g, 0.1f * g);
        float p = exp2f(v * rinvP[m][q]);   // max-free: |arg| bounded
        if (m == 2) p = hiz ? p : 0.f;      // zero pad-rows 36..47
        psP[n] += p;
        numP[n] = fmaf(p, g, numP[n]);
        pb[q] = (__bf16)p;
      }
      *(uint2*)&mybuf[(n * 16 + lo) * ASTR + m * 16 + hi * 4] =
          __builtin_bit_cast(uint2, pb);
    }
  }
  #pragma unroll
  for (int n = 0; n < 3; ++n) {
    numP[n] += __shfl_xor(numP[n], 16); numP[n] += __shfl_xor(numP[n], 32);
    psP[n]  += __shfl_xor(psP[n], 16);  psP[n]  += __shfl_xor(psP[n], 32);
  }
  WAVE_SYNC();

  // ======== gA (once; reused for both matvecs) =============================
  bf16x8 gA[3][2];
  const u16* gp = gram_bf + (size_t)i * (RP * KP);
  #pragma unroll
  for (int m = 0; m < 3; ++m)
    #pragma unroll
    for (int kt = 0; kt < 2; ++kt)
      gA[m][kt] = __builtin_bit_cast(bf16x8,
          *(const uint4*)(gp + (m * 16 + lo) * KP + (kt << 5) + (hi << 3)));

  // ======== matvec_P + wn2_P + LSE_P ======================================
  {
    floatx4 tP[3][3];
    #pragma unroll
    for (int m = 0; m < 3; ++m)
      #pragma unroll
      for (int n = 0; n < 3; ++n) tP[m][n] = floatx4{0.f, 0.f, 0.f, 0.f};
    #pragma unroll
    for (int kt = 0; kt < 2; ++kt) {
      bf16x8 gB[3];
      #pragma unroll
      for (int n = 0; n < 3; ++n) {
        const uint2* bp = (const uint2*)&mybuf[(n * 16 + lo) * ASTR + (kt << 5) + (hi << 3)];
        uint2 b0 = bp[0], b1 = bp[1];
        uint4 bb; bb.x = b0.x; bb.y = b0.y; bb.z = b1.x; bb.w = b1.y;
        gB[n] = __builtin_bit_cast(bf16x8, bb);
      }
      #pragma unroll
      for (int m = 0; m < 3; ++m)
        #pragma unroll
        for (int n = 0; n < 3; ++n)
          tP[m][n] = __builtin_amdgcn_mfma_f32_16x16x32_bf16(gA[m][kt], gB[n], tP[m][n], 0, 0, 0);
    }
    float e4 = 0.f;
    #pragma unroll
    for (int n = 0; n < 3; ++n) {
      float w = 0.f;
      #pragma unroll
      for (int m = 0; m < 3; ++m) {
        uint2 av = *(const uint2*)&mybuf[(n * 16 + lo) * ASTR + m * 16 + hi * 4];
        w = fmaf(bflo(av.x), tP[m][n][0], w);
        w = fmaf(bfhi(av.x), tP[m][n][1], w);
        w = fmaf(bflo(av.y), tP[m][n][2], w);
        w = fmaf(bfhi(av.y), tP[m][n][3], w);
      }
      w += __shfl_xor(w, 16);
      w += __shfl_xor(w, 32);     // full sum over r (hi-duplicated)
      const int col = n * 16 + lo;
      if (col < lenP) {
        float inv = __builtin_amdgcn_rcpf(psP[n]);
        float wn2 = fmaxf(w * inv * inv, 0.f);
        float nm  = numP[n] * inv;
        float den = fmaxf(sqrtf(wn2) * cn[j0 * LL + col], 1e-8f);
        float sim = nm * __builtin_amdgcn_rcpf(den);
        e4 += exp2f(sim * 8.656170245333781f);   // 6*log2e
      }
    }
    // values identical across hi groups -> reduce over lo only
    #pragma unroll
    for (int off = 1; off < 16; off <<= 1) e4 += __shfl_xor(e4, off);
    if (lane == 0 && lenP <= 48)
      scores[i * NN + j0] = log2f(e4) * 0.11552453009332421f; // ln2/6
  }
  WAVE_SYNC();   // drain LDS reads before pair-Q overwrites the region

  // ======== ss_Q -> rinv_Q ================================================
  float ssQ[3][4];
  #pragma unroll
  for (int m = 0; m < 3; ++m)
    #pragma unroll
    for (int q = 0; q < 4; ++q) ssQ[m][q] = 0.f;
  {
    float mk[3];
    #pragma unroll
    for (int n = 0; n < 3; ++n) mk[n] = (n * 16 + lo < lenQ) ? 1.f : 0.f;
    #pragma unroll
    for (int m = 0; m < 3; ++m)
      #pragma unroll
      for (int n = 0; n < 3; ++n)
        #pragma unroll
        for (int q = 0; q < 4; ++q) {
          float g = aQ[m][n][q];
          float v = fmaxf(g, 0.1f * g);
          ssQ[m][q] = fmaf(v * v, mk[n], ssQ[m][q]);
        }
  }
  #pragma unroll
  for (int off = 1; off < 16; off <<= 1)
    #pragma unroll
    for (int m = 0; m < 3; ++m)
      #pragma unroll
      for (int q = 0; q < 4; ++q)
        ssQ[m][q] += __shfl_xor(ssQ[m][q], off);
  float rinvQ[3][4];
  #pragma unroll
  for (int m = 0; m < 3; ++m)
    #pragma unroll
    for (int q = 0; q < 4; ++q)
      rinvQ[m][q] = 12.984255368000671f / (sqrtf(ssQ[m][q]) + 1e-8f);

  // ======== softmax_Q -> LDS ==============================================
  float numQ[3], psQ[3];
  #pragma unroll
  for (int n = 0; n < 3; ++n) { numQ[n] = 0.f; psQ[n] = 0.f; }
  #pragma unroll
  for (int m = 0; m < 3; ++m) {
    #pragma unroll
    for (int n = 0; n < 3; ++n) {
      bf16x4 pb;
      #pragma unroll
      for (int q = 0; q < 4; ++q) {
        float g = aQ[m][n][q];
        float v = fmaxf(g, 0.1f * g);
        float p = exp2f(v * rinvQ[m][q]);
        if (m == 2) p = hiz ? p : 0.f;
        psQ[n] += p;
        numQ[n] = fmaf(p, g, numQ[n]);
        pb[q] = (__bf16)p;
      }
      *(uint2*)&mybuf[(n * 16 + lo) * ASTR + m * 16 + hi * 4] =
          __builtin_bit_cast(uint2, pb);
    }
  }
  #pragma unroll
  for (int n = 0; n < 3; ++n) {
    numQ[n] += __shfl_xor(numQ[n], 16); numQ[n] += __shfl_xor(numQ[n], 32);
    psQ[n]  += __shfl_xor(psQ[n], 16);  psQ[n]  += __shfl_xor(psQ[n], 32);
  }
  WAVE_SYNC();

  // ======== matvec_Q + wn2_Q + LSE_Q ======================================
  {
    floatx4 tQ[3][3];
    #pragma unroll
    for (int m = 0; m < 3; ++m)
      #pragma unroll
      for (int n = 0; n < 3; ++n) tQ[m][n] = floatx4{0.f, 0.f, 0.f, 0.f};
    #pragma unroll
    for (int kt = 0; kt < 2; ++kt) {
      bf16x8 gB[3];
      #pragma unroll
      for (int n = 0; n < 3; ++n) {
        const uint2* bp = (const uint2*)&mybuf[(n * 16 + lo) * ASTR + (kt << 5) + (hi << 3)];
        uint2 b0 = bp[0], b1 = bp[1];
        uint4 bb; bb.x = b0.x; bb.y = b0.y; bb.z = b1.x; bb.w = b1.y;
        gB[n] = __builtin_bit_cast(bf16x8, bb);
      }
      #pragma unroll
      for (int m = 0; m < 3; ++m)
        #pragma unroll
        for (int n = 0; n < 3; ++n)
          tQ[m][n] = __builtin_amdgcn_mfma_f32_16x16x32_bf16(gA[m][kt], gB[n], tQ[m][n], 0, 0, 0);
    }
    float e4 = 0.f;
    #pragma unroll
    for (int n = 0; n < 3; ++n) {
      float w = 0.f;
      #pragma unroll
      for (int m = 0; m < 3; ++m) {
        uint2 av = *(const uint2*)&mybuf[(n * 16 + lo) * ASTR + m * 16 + hi * 4];
        w = fmaf(bflo(av.x), tQ[m][n][0], w);
        w = fmaf(bfhi(av.x), tQ[m][n][1], w);
        w = fmaf(bflo(av.y), tQ[m][n][2], w);
        w = fmaf(bfhi(av.y), tQ[m][n][3], w);
      }
      w += __shfl_xor(w, 16);
      w += __shfl_xor(w, 32);
      const int col = n * 16 + lo;
      if (col < lenQ) {
        float inv = __builtin_amdgcn_rcpf(psQ[n]);
        float wn2 = fmaxf(w * inv * inv, 0.f);
        float nm  = numQ[n] * inv;
        float den = fmaxf(sqrtf(wn2) * cn[j1 * LL + col], 1e-8f);
        float sim = nm * __builtin_amdgcn_rcpf(den);
        e4 += exp2f(sim * 8.656170245333781f);
      }
    }
    #pragma unroll
    for (int off = 1; off < 16; off <<= 1) e4 += __shfl_xor(e4, off);
    if (lane == 0 && lenQ <= 48)
      scores[i * NN + j1] = log2f(e4) * 0.11552453009332421f;
  }
}

// ---- xattn4: len>48 pairs, COMPACT launch (grid-stride over list) ---------
__global__ __launch_bounds__(256, 4) void xattn4_kernel(
    const u16* __restrict__ im_bf, const u16* __restrict__ s_bf,
    const u16* __restrict__ gram_bf, const float* __restrict__ cn,
    const int* __restrict__ cap, float* __restrict__ scores,
    const int* __restrict__ longcnt, const int* __restrict__ longlist) {
  __shared__ u16 buf[(4 * WROWS + SLOP) * ASTR];

  const int wid  = threadIdx.x >> 6;
  const int lane = threadIdx.x & 63;
  const int lo = lane & 15, hi = lane >> 4;
  const int nlong = longcnt[0];
  const int nitems = nlong << 8;        // 256 images per long caption
  u16* mybuf = buf + wid * (WROWS * ASTR);

  if (lane < WROWS) {
    uint2 z2 = {0u, 0u};
    uint2* zp = (uint2*)&mybuf[lane * ASTR + 48];
    zp[0] = z2; zp[1] = z2; zp[2] = z2; zp[3] = z2;
  }

  for (int item = (blockIdx.x << 2) | wid; item < nitems; item += 4096) {
    const int i = item & 255;
    const int j = longlist[item >> 8];
    const int len = cap[j];

    floatx4 acc[3][4];
    #pragma unroll
    for (int m = 0; m < 3; ++m)
      #pragma unroll
      for (int n = 0; n < 4; ++n) acc[m][n] = floatx4{0.f, 0.f, 0.f, 0.f};

    const u16* imp = im_bf + (size_t)i * (RP * DD);
    const u16* sp  = s_bf  + (size_t)j * (LP * DD);

    #pragma unroll 2
    for (int kt = 0; kt < 8; ++kt) {
      const int k0 = (kt << 5) + (hi << 3);
      bf16x8 af[3], bfr[4];
      #pragma unroll
      for (int m = 0; m < 3; ++m)
        af[m] = __builtin_bit_cast(bf16x8, *(const uint4*)(imp + (m * 16 + lo) * DD + k0));
      #pragma unroll
      for (int n = 0; n < 4; ++n)
        bfr[n] = __builtin_bit_cast(bf16x8, *(const uint4*)(sp + (n * 16 + lo) * DD + k0));
      #pragma unroll
      for (int m = 0; m < 3; ++m)
        #pragma unroll
        for (int n = 0; n < 4; ++n)
          acc[m][n] = __builtin_amdgcn_mfma_f32_16x16x32_bf16(af[m], bfr[n], acc[m][n], 0, 0, 0);
    }

    float maskf[4];
    #pragma unroll
    for (int n = 0; n < 4; ++n) maskf[n] = (n * 16 + lo < len) ? 1.f : 0.f;

    float ss[3][4];
    #pragma unroll
    for (int m = 0; m < 3; ++m)
      #pragma unroll
      for (int q = 0; q < 4; ++q) ss[m][q] = 0.f;
    #pragma unroll
    for (int m = 0; m < 3; ++m)
      #pragma unroll
      for (int n = 0; n < 4; ++n)
        #pragma unroll
        for (int q = 0; q < 4; ++q) {
          float g = acc[m][n][q];
          float v = fmaxf(g, 0.1f * g);
          ss[m][q] = fmaf(v * v, maskf[n], ss[m][q]);
        }
    #pragma unroll
    for (int off = 1; off < 16; off <<= 1)
      #pragma unroll
      for (int m = 0; m < 3; ++m)
        #pragma unroll
        for (int q = 0; q < 4; ++q)
          ss[m][q] += __shfl_xor(ss[m][q], off);

    float rinv[3][4];
    #pragma unroll
    for (int m = 0; m < 3; ++m)
      #pragma unroll
      for (int q = 0; q < 4; ++q)
        rinv[m][q] = 12.984255368000671f / (sqrtf(ss[m][q]) + 1e-8f);

    const bool hiz = (hi == 0);
    float num[4], psum[4];
    #pragma unroll
    for (int n = 0; n < 4; ++n) { num[n] = 0.f; psum[n] = 0.f; }

    #pragma unroll
    for (int m = 0; m < 3; ++m) {
      #pragma unroll
      for (int n = 0; n < 4; ++n) {
        bf16x4 pb;
        #pragma unroll
        for (int q = 0; q < 4; ++q) {
          float g = acc[m][n][q];
          float v = fmaxf(g, 0.1f * g);
          float p = exp2f(v * rinv[m][q]);
          if (m == 2) p = hiz ? p : 0.f;
          psum[n] += p;
          num[n] = fmaf(p, g, num[n]);
          pb[q] = (__bf16)p;
        }
        if (n < 3 || lo < 2)
          *(uint2*)&mybuf[(n * 16 + lo) * ASTR + m * 16 + hi * 4] =
              __builtin_bit_cast(uint2, pb);
      }
    }
    #pragma unroll
    for (int n = 0; n < 4; ++n) {
      num[n]  += __shfl_xor(num[n], 16);  num[n]  += __shfl_xor(num[n], 32);
      psum[n] += __shfl_xor(psum[n], 16); psum[n] += __shfl_xor(psum[n], 32);
    }
    WAVE_SYNC();

    bf16x8 gA[3][2];
    const u16* gp = gram_bf + (size_t)i * (RP * KP);
    #pragma unroll
    for (int m = 0; m < 3; ++m)
      #pragma unroll
      for (int kt = 0; kt < 2; ++kt)
        gA[m][kt] = __builtin_bit_cast(bf16x8,
            *(const uint4*)(gp + (m * 16 + lo) * KP + (kt << 5) + (hi << 3)));

    floatx4 tac[3][4];
    #pragma unroll
    for (int m = 0; m < 3; ++m)
      #pragma unroll
      for (int n = 0; n < 4; ++n) tac[m][n] = floatx4{0.f, 0.f, 0.f, 0.f};

    #pragma unroll
    for (int kt = 0; kt < 2; ++kt) {
      bf16x8 gB[4];
      #pragma unroll
      for (int n = 0; n < 4; ++n) {
        const uint2* bp = (const uint2*)&mybuf[(n * 16 + lo) * ASTR + (kt << 5) + (hi << 3)];
        uint2 b0 = bp[0], b1 = bp[1];
        uint4 bb; bb.x = b0.x; bb.y = b0.y; bb.z = b1.x; bb.w = b1.y;
        gB[n] = __builtin_bit_cast(bf16x8, bb);
      }
      #pragma unroll
      for (int m = 0; m < 3; ++m)
        #pragma unroll
        for (int n = 0; n < 4; ++n)
          tac[m][n] = __builtin_amdgcn_mfma_f32_16x16x32_bf16(gA[m][kt], gB[n], tac[m][n], 0, 0, 0);
    }

    float e4 = 0.f;
    #pragma unroll
    for (int n = 0; n < 4; ++n) {
      float w = 0.f;
      #pragma unroll
      for (int m = 0; m < 3; ++m) {
        uint2 av = *(const uint2*)&mybuf[(n * 16 + lo) * ASTR + m * 16 + hi * 4];
        w = fmaf(bflo(av.x), tac[m][n][0], w);
        w = fmaf(bfhi(av.x), tac[m][n][1], w);
        w = fmaf(bflo(av.y), tac[m][n][2], w);
        w = fmaf(bfhi(av.y), tac[m][n][3], w);
      }
      w += __shfl_xor(w, 16);
      w += __shfl_xor(w, 32);
      const int col = n * 16 + lo;
      if (col < len) {
        float inv = __builtin_amdgcn_rcpf(psum[n]);
        float wn2 = fmaxf(w * inv * inv, 0.f);
        float nm  = num[n] * inv;
        float den = fmaxf(sqrtf(wn2) * cn[j * LL + col], 1e-8f);
        float sim = nm * __builtin_amdgcn_rcpf(den);
        e4 += exp2f(sim * 8.656170245333781f);
      }
    }
    #pragma unroll
    for (int off = 1; off < 64; off <<= 1) e4 += __shfl_xor(e4, off);
    if (lane == 0)
      scores[i * NN + j] = (log2f(e4) - 2.0f) * 0.11552453009332421f;
    WAVE_SYNC();   // drain LDS reads before next item overwrites mybuf
  }
}

// ---- loss: hinge terms vs diagonal, full reduction ------------------------
__global__ void loss_kernel(const float* __restrict__ sc, float* __restrict__ out) {
  __shared__ float diag[NN];
  __shared__ float wsum[4];
  const int t = threadIdx.x;
  diag[t] = sc[t * NN + t];
  __syncthreads();
  const float di = diag[t];
  const float4* row = (const float4*)(sc + t * NN);
  float acc = 0.f;
  for (int q = 0; q < 64; ++q) {
    float4 v = row[q];
    const int b = q * 4;
    if (b + 0 != t) acc += fmaxf(0.2f + v.x - di, 0.f) + fmaxf(0.2f + v.x - diag[b + 0], 0.f);
    if (b + 1 != t) acc += fmaxf(0.2f + v.y - di, 0.f) + fmaxf(0.2f + v.y - diag[b + 1], 0.f);
    if (b + 2 != t) acc += fmaxf(0.2f + v.z - di, 0.f) + fmaxf(0.2f + v.z - diag[b + 2], 0.f);
    if (b + 3 != t) acc += fmaxf(0.2f + v.w - di, 0.f) + fmaxf(0.2f + v.w - diag[b + 3], 0.f);
  }
  #pragma unroll
  for (int o = 32; o; o >>= 1) acc += __shfl_xor(acc, o);
  if ((t & 63) == 0) wsum[t >> 6] = acc;
  __syncthreads();
  if (t == 0) out[0] = wsum[0] + wsum[1] + wsum[2] + wsum[3];
}

// ---------------------------------------------------------------------------
extern "C" void kernel_launch(void* const* d_in, const int* in_sizes, int n_in,
                              void* d_out, int out_size, void* d_ws, size_t ws_size,
                              hipStream_t stream) {
  const float* im = (const float*)d_in[0];
  const float* s  = (const float*)d_in[1];
  const int* cap  = (const int*)d_in[2];
  float* out = (float*)d_out;

  char* ws = (char*)d_ws;
  u16*   im_bf   = (u16*)(ws);                         //  6,291,456 B
  u16*   s_bf    = (u16*)(ws + 6291456);               //  8,388,608 B
  u16*   gram_bf = (u16*)(ws + 14680064);              //  1,572,864 B
  float* cn      = (float*)(ws + 16252928);            //     51,200 B
  float* scores  = (float*)(ws + 16304128);            //    262,144 B
  int*   longcnt = (int*)(ws + 16566272);              //          4 B
  int*   longlst = (int*)(ws + 16566276);              //      1,024 B

  hipMemsetAsync(longcnt, 0, 4, stream);
  prep_kernel<<<dim3(2 * NN), dim3(256), 0, stream>>>(im, s, cap, im_bf, gram_bf,
                                                      s_bf, cn, longcnt, longlst);
  xattn_main_kernel<<<dim3(NN * 32), dim3(256), 0, stream>>>(im_bf, s_bf, gram_bf, cn, cap, scores);
  xattn4_kernel<<<dim3(1024), dim3(256), 0, stream>>>(im_bf, s_bf, gram_bf, cn, cap, scores,
                                                      longcnt, longlst);
  loss_kernel<<<dim3(1), dim3(256), 0, stream>>>(scores, out);
}

// Round 11
// 358.383 us; speedup vs baseline: 1.6088x; 1.6088x over previous
//
#include <hip/hip_runtime.h>

// ---------------------------------------------------------------------------
// ContrastiveLoss (SCAN t2i cross-attention) on MI355X — round 11.
// N=256x256 pairs, R=36 regions, L=50 words, D=256.
// r11 vs r9/r10: attack the measured ~7 TB/s L2-miss traffic ceiling.
// Block = 512 thr (8 waves) = one image x 32 captions; im_i staged ONCE in
// LDS (phase-A A-frags from LDS); Gram frags held in regs across the j-loop.
// Per-pair global traffic 48KB -> 24KB. Long captions (len>48) via xattn4.
// ---------------------------------------------------------------------------

typedef unsigned short u16;
typedef unsigned int u32;

typedef __attribute__((ext_vector_type(8))) __bf16 bf16x8;
typedef __attribute__((ext_vector_type(4))) __bf16 bf16x4;
typedef __attribute__((ext_vector_type(4))) float floatx4;

#define NN 256
#define RR 36
#define LL 50
#define DD 256
#define RP 48    // padded region dim
#define LP 64    // padded word dim (s rows)
#define KP 64    // gram row stride / matvec K
#define ASTR 68  // u16 stride of p-buffer rows
#define ISTR 264 // u16 stride of LDS im rows (528B: 2-way alias only)
#define WROWS 50 // xattn4 LDS rows per wave
#define SLOP 14  // xattn4 shared overflow rows
#define PSTR 264 // u16 stride for prep LDS stage

__device__ __forceinline__ u16 f2bf(float v) {
  u32 u = __builtin_bit_cast(u32, v);
  u += 0x7fffu + ((u >> 16) & 1u);   // RNE (inputs never NaN)
  return (u16)(u >> 16);
}
__device__ __forceinline__ float bflo(u32 w) { return __builtin_bit_cast(float, w << 16); }
__device__ __forceinline__ float bfhi(u32 w) { return __builtin_bit_cast(float, w & 0xffff0000u); }

#define WAVE_SYNC() do { \
  asm volatile("s_waitcnt lgkmcnt(0)" ::: "memory"); \
  __builtin_amdgcn_sched_barrier(0); \
} while (0)

// ---- fused prep: blocks 0..255 im+gram; blocks 256..511 s+cn+longlist -----
__global__ void prep_kernel(const float* __restrict__ im,
                            const float* __restrict__ s,
                            const int* __restrict__ cap,
                            u16* __restrict__ im_bf,
                            u16* __restrict__ gram_bf,
                            u16* __restrict__ s_bf,
                            float* __restrict__ cn,
                            int* __restrict__ longcnt,
                            int* __restrict__ longlist) {
  __shared__ u16 Lb[RP * PSTR];
  const int t = threadIdx.x;
  if (blockIdx.x < NN) {
    const int i = blockIdx.x;
    const float* src = im + (size_t)i * (RR * DD);
    u16* dst = im_bf + (size_t)i * (RP * DD);
    for (int e = t; e < RR * DD; e += 256) {
      int r = e >> 8, d = e & 255;
      u16 b = f2bf(src[e]);
      dst[e] = b;
      Lb[r * PSTR + d] = b;
    }
    for (int e = RR * DD + t; e < RP * DD; e += 256) {
      int r = e >> 8, d = e & 255;
      dst[e] = 0;
      Lb[r * PSTR + d] = 0;
    }
    __syncthreads();
    if (t >= 64) return;   // wave 0 computes Gram via MFMA from LDS
    const int lane = t;
    const int lo = lane & 15, hi = lane >> 4;
    floatx4 acc[3][3];
    #pragma unroll
    for (int m = 0; m < 3; ++m)
      #pragma unroll
      for (int n = 0; n < 3; ++n) acc[m][n] = floatx4{0.f, 0.f, 0.f, 0.f};
    #pragma unroll 2
    for (int kt = 0; kt < 8; ++kt) {
      const int k0 = (kt << 5) + (hi << 3);
      bf16x8 f[3];
      #pragma unroll
      for (int m = 0; m < 3; ++m)
        f[m] = __builtin_bit_cast(bf16x8, *(const uint4*)&Lb[(m * 16 + lo) * PSTR + k0]);
      #pragma unroll
      for (int m = 0; m < 3; ++m)
        #pragma unroll
        for (int n = 0; n < 3; ++n)
          acc[m][n] = __builtin_amdgcn_mfma_f32_16x16x32_bf16(f[m], f[n], acc[m][n], 0, 0, 0);
    }
    u16* g = gram_bf + (size_t)i * (RP * KP);
    #pragma unroll
    for (int m = 0; m < 3; ++m)
      #pragma unroll
      for (int n = 0; n < 3; ++n)
        #pragma unroll
        for (int q = 0; q < 4; ++q)
          g[(m * 16 + hi * 4 + q) * KP + n * 16 + lo] = f2bf(acc[m][n][q]);
    for (int e = lane; e < RP * 16; e += 64) {
      int r = e >> 4, c = e & 15;
      g[r * KP + 48 + c] = 0;
    }
  } else {
    const int j = blockIdx.x - NN;
    const float* src = s + (size_t)j * (LL * DD);
    u16* dst = s_bf + (size_t)j * (LP * DD);
    for (int e = t; e < LL * DD; e += 256) dst[e] = f2bf(src[e]);
    for (int e = LL * DD + t; e < LP * DD; e += 256) dst[e] = 0;
    const int l = t >> 2, q = t & 3;
    float acc = 0.f;
    if (l < LL) {
      const float* row = src + l * DD + q * 64;
      #pragma unroll 4
      for (int d = 0; d < 64; ++d) { float v = row[d]; acc = fmaf(v, v, acc); }
    }
    acc += __shfl_xor(acc, 1);
    acc += __shfl_xor(acc, 2);
    if (l < LL && q == 0) cn[j * LL + l] = sqrtf(acc);
    if (t == 0 && cap[j] > 48) {
      int k = atomicAdd(longcnt, 1);
      longlist[k] = j;
    }
  }
}

// ---- xattn_main: 8 waves/block, 1 image x 32 captions, im in LDS ----------
__global__ __launch_bounds__(512, 4) void xattn_main_kernel(
    const u16* __restrict__ im_bf, const u16* __restrict__ s_bf,
    const u16* __restrict__ gram_bf, const float* __restrict__ cn,
    const int* __restrict__ cap, float* __restrict__ scores) {
  __shared__ u16 Lim[RP * ISTR];        // 25,344 B (image tile, bf16)
  __shared__ u16 pbuf[8][RP * ASTR];    // 8 x 6,528 B (per-wave p-buffers)

  const int t    = threadIdx.x;
  const int wid  = t >> 6;
  const int lane = t & 63;
  const int lo = lane & 15, hi = lane >> 4;
  const int i  = blockIdx.x >> 3;
  const int jg = blockIdx.x & 7;
  const bool hiz = (hi == 0);

  // ---- stage im_i into LDS (48x256 bf16, row stride 264) ------------------
  {
    const u16* imp = im_bf + (size_t)i * (RP * DD);
    #pragma unroll
    for (int k = 0; k < 3; ++k) {
      int f = t + (k << 9);             // 0..1535 uint4s
      int row = f >> 5, c8 = f & 31;
      *(uint4*)&Lim[row * ISTR + (c8 << 3)] =
          *(const uint4*)(imp + row * DD + (c8 << 3));
    }
  }
  u16* mybuf = pbuf[wid];
  if (lane < RP) {   // zero K-pad cols 48..63 once (never overwritten)
    uint2 z2 = {0u, 0u};
    uint2* zp = (uint2*)&mybuf[lane * ASTR + 48];
    zp[0] = z2; zp[1] = z2; zp[2] = z2; zp[3] = z2;
  }

  // ---- Gram A-fragments: once per block (i-invariant) ---------------------
  bf16x8 gA[3][2];
  {
    const u16* gp = gram_bf + (size_t)i * (RP * KP);
    #pragma unroll
    for (int m = 0; m < 3; ++m)
      #pragma unroll
      for (int kt = 0; kt < 2; ++kt)
        gA[m][kt] = __builtin_bit_cast(bf16x8,
            *(const uint4*)(gp + (m * 16 + lo) * KP + (kt << 5) + (hi << 3)));
  }
  __syncthreads();   // im tile ready

  // ---- loop over this wave's 4 captions -----------------------------------
  for (int jj = 0; jj < 4; ++jj) {
    const int j = (jg << 5) | (wid << 2) | jj;
    const int len = cap[j];
    if (len > 48) continue;             // wave-uniform; handled by xattn4

    // ==== Phase A: G = im_i @ s_j^T (A from LDS, B from global) ===========
    floatx4 acc[3][3];
    #pragma unroll
    for (int m = 0; m < 3; ++m)
      #pragma unroll
      for (int n = 0; n < 3; ++n) acc[m][n] = floatx4{0.f, 0.f, 0.f, 0.f};

    const u16* sp = s_bf + (size_t)j * (LP * DD);

    #pragma unroll 2
    for (int kt = 0; kt < 8; ++kt) {
      const int k0 = (kt << 5) + (hi << 3);
      bf16x8 af[3], bfr[3];
      #pragma unroll
      for (int n = 0; n < 3; ++n)
        bfr[n] = __builtin_bit_cast(bf16x8, *(const uint4*)(sp + (n * 16 + lo) * DD + k0));
      #pragma unroll
      for (int m = 0; m < 3; ++m)
        af[m] = __builtin_bit_cast(bf16x8, *(const uint4*)&Lim[(m * 16 + lo) * ISTR + k0]);
      #pragma unroll
      for (int m = 0; m < 3; ++m)
        #pragma unroll
        for (int n = 0; n < 3; ++n)
          acc[m][n] = __builtin_amdgcn_mfma_f32_16x16x32_bf16(af[m], bfr[n], acc[m][n], 0, 0, 0);
    }

    // ==== row norms in-fragment ============================================
    float ss[3][4];
    #pragma unroll
    for (int m = 0; m < 3; ++m)
      #pragma unroll
      for (int q = 0; q < 4; ++q) ss[m][q] = 0.f;
    {
      float mk[3];
      #pragma unroll
      for (int n = 0; n < 3; ++n) mk[n] = (n * 16 + lo < len) ? 1.f : 0.f;
      #pragma unroll
      for (int m = 0; m < 3; ++m)
        #pragma unroll
        for (int n = 0; n < 3; ++n)
          #pragma unroll
          for (int q = 0; q < 4; ++q) {
            float g = acc[m][n][q];
            float v = fmaxf(g, 0.1f * g);
            ss[m][q] = fmaf(v * v, mk[n], ss[m][q]);
          }
    }
    #pragma unroll
    for (int off = 1; off < 16; off <<= 1)
      #pragma unroll
      for (int m = 0; m < 3; ++m)
        #pragma unroll
        for (int q = 0; q < 4; ++q)
          ss[m][q] += __shfl_xor(ss[m][q], off);
    float rinv[3][4];
    #pragma unroll
    for (int m = 0; m < 3; ++m)
      #pragma unroll
      for (int q = 0; q < 4; ++q)
        rinv[m][q] = 12.984255368000671f / (sqrtf(ss[m][q]) + 1e-8f); // 9*log2e/(||.||+eps)

    // ==== softmax weights + num/psum; p -> LDS [l][r] ======================
    float num[3], psum[3];
    #pragma unroll
    for (int n = 0; n < 3; ++n) { num[n] = 0.f; psum[n] = 0.f; }
    #pragma unroll
    for (int m = 0; m < 3; ++m) {
      #pragma unroll
      for (int n = 0; n < 3; ++n) {
        bf16x4 pb;
        #pragma unroll
        for (int q = 0; q < 4; ++q) {
          float g = acc[m][n][q];
          float v = fmaxf(g, 0.1f * g);
          float p = exp2f(v * rinv[m][q]);   // max-free: |arg| bounded
          if (m == 2) p = hiz ? p : 0.f;     // zero pad-rows 36..47
          psum[n] += p;
          num[n] = fmaf(p, g, num[n]);
          pb[q] = (__bf16)p;
        }
        *(uint2*)&mybuf[(n * 16 + lo) * ASTR + m * 16 + hi * 4] =
            __builtin_bit_cast(uint2, pb);
      }
    }
    #pragma unroll
    for (int n = 0; n < 3; ++n) {
      num[n]  += __shfl_xor(num[n], 16);  num[n]  += __shfl_xor(num[n], 32);
      psum[n] += __shfl_xor(psum[n], 16); psum[n] += __shfl_xor(psum[n], 32);
    }
    WAVE_SYNC();

    // ==== matvec: t = Gram_i @ p ==========================================
    floatx4 tac[3][3];
    #pragma unroll
    for (int m = 0; m < 3; ++m)
      #pragma unroll
      for (int n = 0; n < 3; ++n) tac[m][n] = floatx4{0.f, 0.f, 0.f, 0.f};
    #pragma unroll
    for (int kt = 0; kt < 2; ++kt) {
      bf16x8 gB[3];
      #pragma unroll
      for (int n = 0; n < 3; ++n) {
        const uint2* bp = (const uint2*)&mybuf[(n * 16 + lo) * ASTR + (kt << 5) + (hi << 3)];
        uint2 b0 = bp[0], b1 = bp[1];
        uint4 bb; bb.x = b0.x; bb.y = b0.y; bb.z = b1.x; bb.w = b1.y;
        gB[n] = __builtin_bit_cast(bf16x8, bb);
      }
      #pragma unroll
      for (int m = 0; m < 3; ++m)
        #pragma unroll
        for (int n = 0; n < 3; ++n)
          tac[m][n] = __builtin_amdgcn_mfma_f32_16x16x32_bf16(gA[m][kt], gB[n], tac[m][n], 0, 0, 0);
    }

    // ==== wn2 + finalize + max-free LSE (lo-reduce; hi-duplicated) =========
    float e4 = 0.f;
    #pragma unroll
    for (int n = 0; n < 3; ++n) {
      float w = 0.f;
      #pragma unroll
      for (int m = 0; m < 3; ++m) {
        uint2 av = *(const uint2*)&mybuf[(n * 16 + lo) * ASTR + m * 16 + hi * 4];
        w = fmaf(bflo(av.x), tac[m][n][0], w);
        w = fmaf(bfhi(av.x), tac[m][n][1], w);
        w = fmaf(bflo(av.y), tac[m][n][2], w);
        w = fmaf(bfhi(av.y), tac[m][n][3], w);
      }
      w += __shfl_xor(w, 16);
      w += __shfl_xor(w, 32);   // full sum over r (hi-duplicated)
      const int col = n * 16 + lo;
      if (col < len) {
        float inv = __builtin_amdgcn_rcpf(psum[n]);
        float wn2 = fmaxf(w * inv * inv, 0.f);
        float nm  = num[n] * inv;
        float den = fmaxf(sqrtf(wn2) * cn[j * LL + col], 1e-8f);
        float sim = nm * __builtin_amdgcn_rcpf(den);
        e4 += exp2f(sim * 8.656170245333781f);   // 6*log2e
      }
    }
    #pragma unroll
    for (int off = 1; off < 16; off <<= 1) e4 += __shfl_xor(e4, off);
    if (lane == 0)
      scores[i * NN + j] = log2f(e4) * 0.11552453009332421f; // ln2/6
    WAVE_SYNC();   // drain LDS reads before next jj overwrites mybuf
  }
}

// ---- xattn4: len>48 pairs, COMPACT launch (grid-stride over list) ---------
__global__ __launch_bounds__(256, 4) void xattn4_kernel(
    const u16* __restrict__ im_bf, const u16* __restrict__ s_bf,
    const u16* __restrict__ gram_bf, const float* __restrict__ cn,
    const int* __restrict__ cap, float* __restrict__ scores,
    const int* __restrict__ longcnt, const int* __restrict__ longlist) {
  __shared__ u16 buf[(4 * WROWS + SLOP) * ASTR];

  const int wid  = threadIdx.x >> 6;
  const int lane = threadIdx.x & 63;
  const int lo = lane & 15, hi = lane >> 4;
  const int nlong = longcnt[0];
  const int nitems = nlong << 8;        // 256 images per long caption
  u16* mybuf = buf + wid * (WROWS * ASTR);

  if (lane < WROWS) {
    uint2 z2 = {0u, 0u};
    uint2* zp = (uint2*)&mybuf[lane * ASTR + 48];
    zp[0] = z2; zp[1] = z2; zp[2] = z2; zp[3] = z2;
  }

  for (int item = (blockIdx.x << 2) | wid; item < nitems; item += 4096) {
    const int i = item & 255;
    const int j = longlist[item >> 8];
    const int len = cap[j];

    floatx4 acc[3][4];
    #pragma unroll
    for (int m = 0; m < 3; ++m)
      #pragma unroll
      for (int n = 0; n < 4; ++n) acc[m][n] = floatx4{0.f, 0.f, 0.f, 0.f};

    const u16* imp = im_bf + (size_t)i * (RP * DD);
    const u16* sp  = s_bf  + (size_t)j * (LP * DD);

    #pragma unroll 2
    for (int kt = 0; kt < 8; ++kt) {
      const int k0 = (kt << 5) + (hi << 3);
      bf16x8 af[3], bfr[4];
      #pragma unroll
      for (int m = 0; m < 3; ++m)
        af[m] = __builtin_bit_cast(bf16x8, *(const uint4*)(imp + (m * 16 + lo) * DD + k0));
      #pragma unroll
      for (int n = 0; n < 4; ++n)
        bfr[n] = __builtin_bit_cast(bf16x8, *(const uint4*)(sp + (n * 16 + lo) * DD + k0));
      #pragma unroll
      for (int m = 0; m < 3; ++m)
        #pragma unroll
        for (int n = 0; n < 4; ++n)
          acc[m][n] = __builtin_amdgcn_mfma_f32_16x16x32_bf16(af[m], bfr[n], acc[m][n], 0, 0, 0);
    }

    float maskf[4];
    #pragma unroll
    for (int n = 0; n < 4; ++n) maskf[n] = (n * 16 + lo < len) ? 1.f : 0.f;

    float ss[3][4];
    #pragma unroll
    for (int m = 0; m < 3; ++m)
      #pragma unroll
      for (int q = 0; q < 4; ++q) ss[m][q] = 0.f;
    #pragma unroll
    for (int m = 0; m < 3; ++m)
      #pragma unroll
      for (int n = 0; n < 4; ++n)
        #pragma unroll
        for (int q = 0; q < 4; ++q) {
          float g = acc[m][n][q];
          float v = fmaxf(g, 0.1f * g);
          ss[m][q] = fmaf(v * v, maskf[n], ss[m][q]);
        }
    #pragma unroll
    for (int off = 1; off < 16; off <<= 1)
      #pragma unroll
      for (int m = 0; m < 3; ++m)
        #pragma unroll
        for (int q = 0; q < 4; ++q)
          ss[m][q] += __shfl_xor(ss[m][q], off);

    float rinv[3][4];
    #pragma unroll
    for (int m = 0; m < 3; ++m)
      #pragma unroll
      for (int q = 0; q < 4; ++q)
        rinv[m][q] = 12.984255368000671f / (sqrtf(ss[m][q]) + 1e-8f);

    const bool hiz = (hi == 0);
    float num[4], psum[4];
    #pragma unroll
    for (int n = 0; n < 4; ++n) { num[n] = 0.f; psum[n] = 0.f; }

    #pragma unroll
    for (int m = 0; m < 3; ++m) {
      #pragma unroll
      for (int n = 0; n < 4; ++n) {
        bf16x4 pb;
        #pragma unroll
        for (int q = 0; q < 4; ++q) {
          float g = acc[m][n][q];
          float v = fmaxf(g, 0.1f * g);
          float p = exp2f(v * rinv[m][q]);
          if (m == 2) p = hiz ? p : 0.f;
          psum[n] += p;
          num[n] = fmaf(p, g, num[n]);
          pb[q] = (__bf16)p;
        }
        if (n < 3 || lo < 2)
          *(uint2*)&mybuf[(n * 16 + lo) * ASTR + m * 16 + hi * 4] =
              __builtin_bit_cast(uint2, pb);
      }
    }
    #pragma unroll
    for (int n = 0; n < 4; ++n) {
      num[n]  += __shfl_xor(num[n], 16);  num[n]  += __shfl_xor(num[n], 32);
      psum[n] += __shfl_xor(psum[n], 16); psum[n] += __shfl_xor(psum[n], 32);
    }
    WAVE_SYNC();

    bf16x8 gA[3][2];
    const u16* gp = gram_bf + (size_t)i * (RP * KP);
    #pragma unroll
    for (int m = 0; m < 3; ++m)
      #pragma unroll
      for (int kt = 0; kt < 2; ++kt)
        gA[m][kt] = __builtin_bit_cast(bf16x8,
            *(const uint4*)(gp + (m * 16 + lo) * KP + (kt << 5) + (hi << 3)));

    floatx4 tac[3][4];
    #pragma unroll
    for (int m = 0; m < 3; ++m)
      #pragma unroll
      for (int n = 0; n < 4; ++n) tac[m][n] = floatx4{0.f, 0.f, 0.f, 0.f};

    #pragma unroll
    for (int kt = 0; kt < 2; ++kt) {
      bf16x8 gB[4];
      #pragma unroll
      for (int n = 0; n < 4; ++n) {
        const uint2* bp = (const uint2*)&mybuf[(n * 16 + lo) * ASTR + (kt << 5) + (hi << 3)];
        uint2 b0 = bp[0], b1 = bp[1];
        uint4 bb; bb.x = b0.x; bb.y = b0.y; bb.z = b1.x; bb.w = b1.y;
        gB[n] = __builtin_bit_cast(bf16x8, bb);
      }
      #pragma unroll
      for (int m = 0; m < 3; ++m)
        #pragma unroll
        for (int n = 0; n < 4; ++n)
          tac[m][n] = __builtin_amdgcn_mfma_f32_16x16x32_bf16(gA[m][kt], gB[n], tac[m][n], 0, 0, 0);
    }

    float e4 = 0.f;
    #pragma unroll
    for (int n = 0; n < 4; ++n) {
      float w = 0.f;
      #pragma unroll
      for (int m = 0; m < 3; ++m) {
        uint2 av = *(const uint2*)&mybuf[(n * 16 + lo) * ASTR + m * 16 + hi * 4];
        w = fmaf(bflo(av.x), tac[m][n][0], w);
        w = fmaf(bfhi(av.x), tac[m][n][1], w);
        w = fmaf(bflo(av.y), tac[m][n][2], w);
        w = fmaf(bfhi(av.y), tac[m][n][3], w);
      }
      w += __shfl_xor(w, 16);
      w += __shfl_xor(w, 32);
      const int col = n * 16 + lo;
      if (col < len) {
        float inv = __builtin_amdgcn_rcpf(psum[n]);
        float wn2 = fmaxf(w * inv * inv, 0.f);
        float nm  = num[n] * inv;
        float den = fmaxf(sqrtf(wn2) * cn[j * LL + col], 1e-8f);
        float sim = nm * __builtin_amdgcn_rcpf(den);
        e4 += exp2f(sim * 8.656170245333781f);
      }
    }
    #pragma unroll
    for (int off = 1; off < 64; off <<= 1) e4 += __shfl_xor(e4, off);
    if (lane == 0)
      scores[i * NN + j] = (log2f(e4) - 2.0f) * 0.11552453009332421f;
    WAVE_SYNC();   // drain LDS reads before next item overwrites mybuf
  }
}

// ---- loss: hinge terms vs diagonal, full reduction ------------------------
__global__ void loss_kernel(const float* __restrict__ sc, float* __restrict__ out) {
  __shared__ float diag[NN];
  __shared__ float wsum[4];
  const int t = threadIdx.x;
  diag[t] = sc[t * NN + t];
  __syncthreads();
  const float di = diag[t];
  const float4* row = (const float4*)(sc + t * NN);
  float acc = 0.f;
  for (int q = 0; q < 64; ++q) {
    float4 v = row[q];
    const int b = q * 4;
    if (b + 0 != t) acc += fmaxf(0.2f + v.x - di, 0.f) + fmaxf(0.2f + v.x - diag[b + 0], 0.f);
    if (b + 1 != t) acc += fmaxf(0.2f + v.y - di, 0.f) + fmaxf(0.2f + v.y - diag[b + 1], 0.f);
    if (b + 2 != t) acc += fmaxf(0.2f + v.z - di, 0.f) + fmaxf(0.2f + v.z - diag[b + 2], 0.f);
    if (b + 3 != t) acc += fmaxf(0.2f + v.w - di, 0.f) + fmaxf(0.2f + v.w - diag[b + 3], 0.f);
  }
  #pragma unroll
  for (int o = 32; o; o >>= 1) acc += __shfl_xor(acc, o);
  if ((t & 63) == 0) wsum[t >> 6] = acc;
  __syncthreads();
  if (t == 0) out[0] = wsum[0] + wsum[1] + wsum[2] + wsum[3];
}

// ---------------------------------------------------------------------------
extern "C" void kernel_launch(void* const* d_in, const int* in_sizes, int n_in,
                              void* d_out, int out_size, void* d_ws, size_t ws_size,
                              hipStream_t stream) {
  const float* im = (const float*)d_in[0];
  const float* s  = (const float*)d_in[1];
  const int* cap  = (const int*)d_in[2];
  float* out = (float*)d_out;

  char* ws = (char*)d_ws;
  u16*   im_bf   = (u16*)(ws);                         //  6,291,456 B
  u16*   s_bf    = (u16*)(ws + 6291456);               //  8,388,608 B
  u16*   gram_bf = (u16*)(ws + 14680064);              //  1,572,864 B
  float* cn      = (float*)(ws + 16252928);            //     51,200 B
  float* scores  = (float*)(ws + 16304128);            //    262,144 B
  int*   longcnt = (int*)(ws + 16566272);              //          4 B
  int*   longlst = (int*)(ws + 16566276);              //      1,024 B

  hipMemsetAsync(longcnt, 0, 4, stream);
  prep_kernel<<<dim3(2 * NN), dim3(256), 0, stream>>>(im, s, cap, im_bf, gram_bf,
                                                      s_bf, cn, longcnt, longlst);
  xattn_main_kernel<<<dim3(NN * 8), dim3(512), 0, stream>>>(im_bf, s_bf, gram_bf, cn, cap, scores);
  xattn4_kernel<<<dim3(1024), dim3(256), 0, stream>>>(im_bf, s_bf, gram_bf, cn, cap, scores,
                                                      longcnt, longlst);
  loss_kernel<<<dim3(1), dim3(256), 0, stream>>>(scores, out);
}